// Round 1
// baseline (812.900 us; speedup 1.0000x reference)
//
#include <hip/hip_runtime.h>

#define ROWS 16

// K1: fused projection GEMM: [feat_src | skip] = feat @ [W_src; W_skip]^T + bias,
// plus el/er attention dots folded into the epilogue via shuffle reduction.
__global__ __launch_bounds__(128) void k1_proj(
    const float* __restrict__ feat,
    const float* __restrict__ Wsrc, const float* __restrict__ bsrc,
    const float* __restrict__ Wskip, const float* __restrict__ bskip,
    const float* __restrict__ attn_l, const float* __restrict__ attn_r,
    float* __restrict__ feat_src, float* __restrict__ skip,
    float* __restrict__ el, float* __restrict__ er, int n)
{
    __shared__ float A[ROWS][128];
    const int tid = threadIdx.x;          // 0..127
    const int row0 = blockIdx.x * ROWS;

    // stage 16x128 fp32 A-tile (8KB), coalesced float4 loads
    const float4* f4 = (const float4*)(feat + (size_t)row0 * 128);
    float4* A4 = (float4*)&A[0][0];
    #pragma unroll
    for (int i = 0; i < 4; ++i) A4[tid + 128*i] = f4[tid + 128*i];
    __syncthreads();

    // each thread owns 2 adjacent output columns c, c+1 of the combined 256
    const int c = tid * 2;
    const float* Wr0; float b0, b1;
    if (c < 128) {
        Wr0 = Wsrc + (size_t)c * 128;
        b0 = bsrc[c]; b1 = bsrc[c + 1];
    } else {
        Wr0 = Wskip + (size_t)(c - 128) * 128;
        b0 = bskip[c - 128]; b1 = bskip[c - 127];
    }
    const float4* W40 = (const float4*)Wr0;
    const float4* W41 = (const float4*)(Wr0 + 128);

    float acc0[ROWS], acc1[ROWS];
    #pragma unroll
    for (int r = 0; r < ROWS; ++r) { acc0[r] = 0.f; acc1[r] = 0.f; }

    for (int k = 0; k < 32; ++k) {
        float4 w0 = W40[k], w1 = W41[k];
        #pragma unroll
        for (int r = 0; r < ROWS; ++r) {
            float4 a = ((const float4*)A[r])[k];   // ds_read_b128, broadcast
            acc0[r] = fmaf(a.x, w0.x, fmaf(a.y, w0.y, fmaf(a.z, w0.z, fmaf(a.w, w0.w, acc0[r]))));
            acc1[r] = fmaf(a.x, w1.x, fmaf(a.y, w1.y, fmaf(a.z, w1.z, fmaf(a.w, w1.w, acc1[r]))));
        }
    }

    #pragma unroll
    for (int r = 0; r < ROWS; ++r) {
        int row = row0 + r;
        if (row < n) {
            float v0 = acc0[r] + b0, v1 = acc1[r] + b1;
            if (c < 128) {
                *(float2*)(feat_src + (size_t)row * 128 + c) = make_float2(v0, v1);
            } else {
                *(float2*)(skip + (size_t)row * 128 + (c - 128)) = make_float2(v0, v1);
            }
        }
    }

    // el/er: wave 0 holds all feat_src columns; head h = 16-lane group
    if (c < 128) {
        const float al0 = attn_l[c], al1 = attn_l[c + 1];
        const float ar0 = attn_r[c], ar1 = attn_r[c + 1];
        const int h = c >> 5;
        #pragma unroll
        for (int r = 0; r < ROWS; ++r) {
            float v0 = acc0[r] + b0, v1 = acc1[r] + b1;
            float pl = v0 * al0 + v1 * al1;
            float pr = v0 * ar0 + v1 * ar1;
            #pragma unroll
            for (int m = 1; m < 16; m <<= 1) {
                pl += __shfl_xor(pl, m);
                pr += __shfl_xor(pr, m);
            }
            int row = row0 + r;
            if ((tid & 15) == 0 && row < n) {
                el[(size_t)row * 4 + h] = pl;
                er[(size_t)row * 4 + h] = pr;
            }
        }
    }
}

// K2: per-edge unnormalized softmax weight w = exp(leaky(el[src]+er[dst]))
// and denominator scatter: esum[dst,h] += w.  (max-subtraction skipped:
// mathematically identical, |e| <= ~5 so exp is safe in fp32)
__global__ __launch_bounds__(256) void k2_edge(
    const int* __restrict__ src, const int* __restrict__ dst,
    const float4* __restrict__ el4, const float4* __restrict__ er4,
    float4* __restrict__ w4, float* __restrict__ esum, int E_)
{
    int e = blockIdx.x * 256 + threadIdx.x;
    if (e >= E_) return;
    int s = src[e], d = dst[e];
    float4 a = el4[s], b = er4[d];
    float4 w; float t;
    t = a.x + b.x; w.x = expf(t >= 0.f ? t : 0.2f * t);
    t = a.y + b.y; w.y = expf(t >= 0.f ? t : 0.2f * t);
    t = a.z + b.z; w.z = expf(t >= 0.f ? t : 0.2f * t);
    t = a.w + b.w; w.w = expf(t >= 0.f ? t : 0.2f * t);
    w4[e] = w;
    float* ep = esum + (size_t)d * 4;
    unsafeAtomicAdd(ep + 0, w.x);
    unsafeAtomicAdd(ep + 1, w.y);
    unsafeAtomicAdd(ep + 2, w.z);
    unsafeAtomicAdd(ep + 3, w.w);
}

// K3: weighted aggregation rst[dst] += (w/esum[dst]) * feat_src[src]
// 2 edges per 256-thread block; 128 lanes = one full HD row per edge.
__global__ __launch_bounds__(256) void k3_aggregate(
    const int* __restrict__ src, const int* __restrict__ dst,
    const float* __restrict__ w, const float* __restrict__ esum,
    const float* __restrict__ feat_src, float* __restrict__ rst, int E_)
{
    int eid = blockIdx.x * 2 + (threadIdx.x >> 7);
    if (eid >= E_) return;
    int j = threadIdx.x & 127;
    int s = src[eid], d = dst[eid];
    int h = j >> 5;
    float coef = w[(size_t)eid * 4 + h] / esum[(size_t)d * 4 + h];
    float val = coef * feat_src[(size_t)s * 128 + j];
    unsafeAtomicAdd(rst + (size_t)d * 128 + j, val);
}

// K4: per-node gated skip + LayerNorm + PReLU, in place on d_out.
// One wave (64 lanes) per node, 2 elements per lane, shuffle reductions.
__global__ __launch_bounds__(256) void k4_epilogue(
    float* __restrict__ out, const float* __restrict__ skip,
    const float* __restrict__ Wg, const float* __restrict__ bg,
    const float* __restrict__ lng, const float* __restrict__ lnb,
    const float* __restrict__ pa, int n)
{
    int node = blockIdx.x * 4 + (threadIdx.x >> 6);
    if (node >= n) return;
    int lane = threadIdx.x & 63;
    int j = lane * 2;
    float2 r = *(const float2*)(out + (size_t)node * 128 + j);
    float2 s = *(const float2*)(skip + (size_t)node * 128 + j);

    // gate = sigmoid(dot([rst, skip, rst-skip], Wg) + bg)
    float g = r.x * Wg[j]     + s.x * Wg[128 + j]     + (r.x - s.x) * Wg[256 + j]
            + r.y * Wg[j + 1] + s.y * Wg[128 + j + 1] + (r.y - s.y) * Wg[256 + j + 1];
    #pragma unroll
    for (int m = 1; m < 64; m <<= 1) g += __shfl_xor(g, m);
    float gate = 1.f / (1.f + expf(-(g + bg[0])));

    float x0 = gate * r.x + (1.f - gate) * s.x;
    float x1 = gate * r.y + (1.f - gate) * s.y;

    // LayerNorm over 128 elements
    float sm = x0 + x1, sq = x0 * x0 + x1 * x1;
    #pragma unroll
    for (int m = 1; m < 64; m <<= 1) {
        sm += __shfl_xor(sm, m);
        sq += __shfl_xor(sq, m);
    }
    float mu = sm * (1.f / 128.f);
    float var = sq * (1.f / 128.f) - mu * mu;
    float rs = rsqrtf(var + 1e-5f);
    float alpha = pa[0];
    float y0 = (x0 - mu) * rs * lng[j]     + lnb[j];
    float y1 = (x1 - mu) * rs * lng[j + 1] + lnb[j + 1];
    y0 = y0 >= 0.f ? y0 : alpha * y0;
    y1 = y1 >= 0.f ? y1 : alpha * y1;
    *(float2*)(out + (size_t)node * 128 + j) = make_float2(y0, y1);
}

extern "C" void kernel_launch(void* const* d_in, const int* in_sizes, int n_in,
                              void* d_out, int out_size, void* d_ws, size_t ws_size,
                              hipStream_t stream)
{
    const float* feat   = (const float*)d_in[0];
    const int*   src    = (const int*)d_in[1];
    const int*   dst    = (const int*)d_in[2];
    const float* Wsrc   = (const float*)d_in[3];
    const float* bsrc   = (const float*)d_in[4];
    const float* attn_l = (const float*)d_in[5];
    const float* attn_r = (const float*)d_in[6];
    const float* Wskip  = (const float*)d_in[7];
    const float* bskip  = (const float*)d_in[8];
    const float* Wg     = (const float*)d_in[9];
    const float* bg     = (const float*)d_in[10];
    const float* lng    = (const float*)d_in[11];
    const float* lnb    = (const float*)d_in[12];
    const float* pa     = (const float*)d_in[13];

    const int n = in_sizes[0] / 128;
    const int E = in_sizes[1];
    float* out = (float*)d_out;

    // workspace layout (fp32): feat_src[n*128] | skip[n*128] | el[n*4] | er[n*4] | w[E*4] | esum[n*4]
    float* ws       = (float*)d_ws;
    float* feat_src = ws;
    float* skip     = feat_src + (size_t)n * 128;
    float* el       = skip + (size_t)n * 128;
    float* er       = el + (size_t)n * 4;
    float* w        = er + (size_t)n * 4;
    float* esum     = w + (size_t)E * 4;

    hipMemsetAsync(esum, 0, (size_t)n * 4 * sizeof(float), stream);
    hipMemsetAsync(out, 0, (size_t)n * 128 * sizeof(float), stream);

    k1_proj<<<(n + ROWS - 1) / ROWS, 128, 0, stream>>>(
        feat, Wsrc, bsrc, Wskip, bskip, attn_l, attn_r, feat_src, skip, el, er, n);
    k2_edge<<<(E + 255) / 256, 256, 0, stream>>>(
        src, dst, (const float4*)el, (const float4*)er, (float4*)w, esum, E);
    k3_aggregate<<<(E + 1) / 2, 256, 0, stream>>>(
        src, dst, w, esum, feat_src, out, E);
    k4_epilogue<<<(n + 3) / 4, 256, 0, stream>>>(
        out, skip, Wg, bg, lng, lnb, pa, n);
}

// Round 2
// 463.230 us; speedup vs baseline: 1.7549x; 1.7549x over previous
//
#include <hip/hip_runtime.h>

#define ROWS 16

// K1: fused projection GEMM: [feat_src | skip] = feat @ [W_src; W_skip]^T + bias,
// plus el/er attention dots folded into the epilogue via shuffle reduction.
__global__ __launch_bounds__(128) void k1_proj(
    const float* __restrict__ feat,
    const float* __restrict__ Wsrc, const float* __restrict__ bsrc,
    const float* __restrict__ Wskip, const float* __restrict__ bskip,
    const float* __restrict__ attn_l, const float* __restrict__ attn_r,
    float* __restrict__ feat_src, float* __restrict__ skip,
    float* __restrict__ el, float* __restrict__ er, int n)
{
    __shared__ float A[ROWS][128];
    const int tid = threadIdx.x;          // 0..127
    const int row0 = blockIdx.x * ROWS;

    const float4* f4 = (const float4*)(feat + (size_t)row0 * 128);
    float4* A4 = (float4*)&A[0][0];
    #pragma unroll
    for (int i = 0; i < 4; ++i) A4[tid + 128*i] = f4[tid + 128*i];
    __syncthreads();

    const int c = tid * 2;
    const float* Wr0; float b0, b1;
    if (c < 128) {
        Wr0 = Wsrc + (size_t)c * 128;
        b0 = bsrc[c]; b1 = bsrc[c + 1];
    } else {
        Wr0 = Wskip + (size_t)(c - 128) * 128;
        b0 = bskip[c - 128]; b1 = bskip[c - 127];
    }
    const float4* W40 = (const float4*)Wr0;
    const float4* W41 = (const float4*)(Wr0 + 128);

    float acc0[ROWS], acc1[ROWS];
    #pragma unroll
    for (int r = 0; r < ROWS; ++r) { acc0[r] = 0.f; acc1[r] = 0.f; }

    for (int k = 0; k < 32; ++k) {
        float4 w0 = W40[k], w1 = W41[k];
        #pragma unroll
        for (int r = 0; r < ROWS; ++r) {
            float4 a = ((const float4*)A[r])[k];
            acc0[r] = fmaf(a.x, w0.x, fmaf(a.y, w0.y, fmaf(a.z, w0.z, fmaf(a.w, w0.w, acc0[r]))));
            acc1[r] = fmaf(a.x, w1.x, fmaf(a.y, w1.y, fmaf(a.z, w1.z, fmaf(a.w, w1.w, acc1[r]))));
        }
    }

    #pragma unroll
    for (int r = 0; r < ROWS; ++r) {
        int row = row0 + r;
        if (row < n) {
            float v0 = acc0[r] + b0, v1 = acc1[r] + b1;
            if (c < 128) {
                *(float2*)(feat_src + (size_t)row * 128 + c) = make_float2(v0, v1);
            } else {
                *(float2*)(skip + (size_t)row * 128 + (c - 128)) = make_float2(v0, v1);
            }
        }
    }

    if (c < 128) {
        const float al0 = attn_l[c], al1 = attn_l[c + 1];
        const float ar0 = attn_r[c], ar1 = attn_r[c + 1];
        const int h = c >> 5;
        #pragma unroll
        for (int r = 0; r < ROWS; ++r) {
            float v0 = acc0[r] + b0, v1 = acc1[r] + b1;
            float pl = v0 * al0 + v1 * al1;
            float pr = v0 * ar0 + v1 * ar1;
            #pragma unroll
            for (int m = 1; m < 16; m <<= 1) {
                pl += __shfl_xor(pl, m);
                pr += __shfl_xor(pr, m);
            }
            int row = row0 + r;
            if ((tid & 15) == 0 && row < n) {
                el[(size_t)row * 4 + h] = pl;
                er[(size_t)row * 4 + h] = pr;
            }
        }
    }
}

// ---- CSR build: histogram -> 3-phase scan -> fill ----

__global__ __launch_bounds__(256) void k_hist(const int* __restrict__ dst,
                                              int* __restrict__ counts, int E_)
{
    int e = blockIdx.x * 256 + threadIdx.x;
    if (e < E_) atomicAdd(&counts[dst[e]], 1);
}

// scanA: per-block (1024 elems, 4/thread) exclusive scan; blocksum[b] = total
__global__ __launch_bounds__(256) void k_scanA(const int* __restrict__ counts,
                                               int* __restrict__ row_start,
                                               int* __restrict__ blocksum, int n)
{
    __shared__ int sdata[256];
    int tid = threadIdx.x;
    int base = blockIdx.x * 1024 + tid * 4;
    int v[4]; int s = 0;
    #pragma unroll
    for (int k = 0; k < 4; ++k) {
        int idx = base + k;
        v[k] = (idx < n) ? counts[idx] : 0;
        s += v[k];
    }
    sdata[tid] = s;
    __syncthreads();
    for (int off = 1; off < 256; off <<= 1) {
        int t = (tid >= off) ? sdata[tid - off] : 0;
        __syncthreads();
        sdata[tid] += t;
        __syncthreads();
    }
    if (tid == 255) blocksum[blockIdx.x] = sdata[255];
    int run = (tid > 0) ? sdata[tid - 1] : 0;
    #pragma unroll
    for (int k = 0; k < 4; ++k) {
        int idx = base + k;
        if (idx < n) row_start[idx] = run;
        run += v[k];
    }
}

// scanB: single block exclusive-scans blocksum (nb <= 128)
__global__ __launch_bounds__(128) void k_scanB(int* __restrict__ blocksum, int nb)
{
    __shared__ int sdata[128];
    int tid = threadIdx.x;
    sdata[tid] = (tid < nb) ? blocksum[tid] : 0;
    __syncthreads();
    for (int off = 1; off < 128; off <<= 1) {
        int t = (tid >= off) ? sdata[tid - off] : 0;
        __syncthreads();
        sdata[tid] += t;
        __syncthreads();
    }
    if (tid < nb) blocksum[tid] = (tid > 0) ? sdata[tid - 1] : 0;
}

// scanC: add block offsets, mirror into cursor, cap with row_start[n]=E
__global__ __launch_bounds__(256) void k_scanC(int* __restrict__ row_start,
                                               const int* __restrict__ blocksum,
                                               int* __restrict__ cursor, int n, int E_)
{
    int i = blockIdx.x * 256 + threadIdx.x;
    if (i < n) {
        int v = row_start[i] + blocksum[i >> 10];
        row_start[i] = v;
        cursor[i] = v;
    }
    if (i == n) row_start[n] = E_;
}

// fill: bucket src ids by dst (order within bucket irrelevant)
__global__ __launch_bounds__(256) void k_fill(const int* __restrict__ src,
                                              const int* __restrict__ dst,
                                              int* __restrict__ cursor,
                                              int* __restrict__ csr_src, int E_)
{
    int e = blockIdx.x * 256 + threadIdx.x;
    if (e >= E_) return;
    int pos = atomicAdd(&cursor[dst[e]], 1);
    csr_src[pos] = src[e];
}

// K3: fused softmax-aggregate + gate + LayerNorm + PReLU.
// One wave (64 lanes) per dst node; lane holds cols j=2*lane, 2*lane+1 (one head).
__global__ __launch_bounds__(256) void k3_fused(
    const int* __restrict__ row_start, const int* __restrict__ csr_src,
    const float* __restrict__ el, const float* __restrict__ er,
    const float* __restrict__ feat_src, const float* __restrict__ skip,
    const float* __restrict__ Wg, const float* __restrict__ bg,
    const float* __restrict__ lng, const float* __restrict__ lnb,
    const float* __restrict__ pa, float* __restrict__ out, int n)
{
    int node = blockIdx.x * 4 + (threadIdx.x >> 6);
    if (node >= n) return;
    int lane = threadIdx.x & 63;
    int j = lane * 2;
    int h = j >> 5;                       // head for both j and j+1

    int beg = row_start[node], end = row_start[node + 1];
    float er_h = er[(size_t)node * 4 + h];

    float acc0 = 0.f, acc1 = 0.f, wsum = 0.f;
    for (int p = beg; p < end; ++p) {
        int s = csr_src[p];
        float t = el[(size_t)s * 4 + h] + er_h;
        float w = __expf(t >= 0.f ? t : 0.2f * t);
        wsum += w;
        float2 f = *(const float2*)(feat_src + (size_t)s * 128 + j);
        acc0 = fmaf(w, f.x, acc0);
        acc1 = fmaf(w, f.y, acc1);
    }
    float inv = (wsum > 0.f) ? 1.f / wsum : 0.f;   // deg-0 node -> rst = 0
    float r0 = acc0 * inv, r1 = acc1 * inv;

    float2 s2 = *(const float2*)(skip + (size_t)node * 128 + j);

    // gate = sigmoid(dot([rst, skip, rst-skip], Wg) + bg)
    float g = r0 * Wg[j]     + s2.x * Wg[128 + j]     + (r0 - s2.x) * Wg[256 + j]
            + r1 * Wg[j + 1] + s2.y * Wg[128 + j + 1] + (r1 - s2.y) * Wg[256 + j + 1];
    #pragma unroll
    for (int m = 1; m < 64; m <<= 1) g += __shfl_xor(g, m);
    float gate = 1.f / (1.f + __expf(-(g + bg[0])));

    float x0 = gate * r0 + (1.f - gate) * s2.x;
    float x1 = gate * r1 + (1.f - gate) * s2.y;

    // LayerNorm over 128
    float sm = x0 + x1, sq = x0 * x0 + x1 * x1;
    #pragma unroll
    for (int m = 1; m < 64; m <<= 1) {
        sm += __shfl_xor(sm, m);
        sq += __shfl_xor(sq, m);
    }
    float mu = sm * (1.f / 128.f);
    float var = sq * (1.f / 128.f) - mu * mu;
    float rs = rsqrtf(var + 1e-5f);
    float alpha = pa[0];
    float y0 = (x0 - mu) * rs * lng[j]     + lnb[j];
    float y1 = (x1 - mu) * rs * lng[j + 1] + lnb[j + 1];
    y0 = y0 >= 0.f ? y0 : alpha * y0;
    y1 = y1 >= 0.f ? y1 : alpha * y1;
    *(float2*)(out + (size_t)node * 128 + j) = make_float2(y0, y1);
}

extern "C" void kernel_launch(void* const* d_in, const int* in_sizes, int n_in,
                              void* d_out, int out_size, void* d_ws, size_t ws_size,
                              hipStream_t stream)
{
    const float* feat   = (const float*)d_in[0];
    const int*   src    = (const int*)d_in[1];
    const int*   dst    = (const int*)d_in[2];
    const float* Wsrc   = (const float*)d_in[3];
    const float* bsrc   = (const float*)d_in[4];
    const float* attn_l = (const float*)d_in[5];
    const float* attn_r = (const float*)d_in[6];
    const float* Wskip  = (const float*)d_in[7];
    const float* bskip  = (const float*)d_in[8];
    const float* Wg     = (const float*)d_in[9];
    const float* bg     = (const float*)d_in[10];
    const float* lng    = (const float*)d_in[11];
    const float* lnb    = (const float*)d_in[12];
    const float* pa     = (const float*)d_in[13];

    const int n = in_sizes[0] / 128;
    const int E = in_sizes[1];
    float* out = (float*)d_out;

    // workspace layout:
    // fp32: feat_src[n*128] | skip[n*128] | el[n*4] | er[n*4]
    // int : counts[n] | row_start[n+1] | cursor[n] | blocksum[128] | csr_src[E]
    float* ws       = (float*)d_ws;
    float* feat_src = ws;
    float* skip     = feat_src + (size_t)n * 128;
    float* el       = skip + (size_t)n * 128;
    float* er       = el + (size_t)n * 4;
    int*   counts    = (int*)(er + (size_t)n * 4);
    int*   row_start = counts + n;
    int*   cursor    = row_start + (n + 1);
    int*   blocksum  = cursor + n;
    int*   csr_src   = blocksum + 128;

    hipMemsetAsync(counts, 0, (size_t)n * sizeof(int), stream);

    k1_proj<<<(n + ROWS - 1) / ROWS, 128, 0, stream>>>(
        feat, Wsrc, bsrc, Wskip, bskip, attn_l, attn_r, feat_src, skip, el, er, n);

    k_hist<<<(E + 255) / 256, 256, 0, stream>>>(dst, counts, E);
    int nb = (n + 1023) / 1024;
    k_scanA<<<nb, 256, 0, stream>>>(counts, row_start, blocksum, n);
    k_scanB<<<1, 128, 0, stream>>>(blocksum, nb);
    k_scanC<<<(n + 256) / 256, 256, 0, stream>>>(row_start, blocksum, cursor, n, E);
    k_fill<<<(E + 255) / 256, 256, 0, stream>>>(src, dst, cursor, csr_src, E);

    k3_fused<<<(n + 3) / 4, 256, 0, stream>>>(
        row_start, csr_src, el, er, feat_src, skip, Wg, bg, lng, lnb, pa, out, n);
}

// Round 3
// 371.732 us; speedup vs baseline: 2.1868x; 1.2461x over previous
//
#include <hip/hip_runtime.h>

typedef __attribute__((ext_vector_type(8))) short short8;
typedef __attribute__((ext_vector_type(4))) float v4f;

__device__ __forceinline__ ushort f2bf(float x) {
    unsigned u = __float_as_uint(x);
    u = u + 0x7fffu + ((u >> 16) & 1u);     // round-to-nearest-even
    return (ushort)(u >> 16);
}
__device__ __forceinline__ float bflo(unsigned u) { return __uint_as_float(u << 16); }
__device__ __forceinline__ float bfhi(unsigned u) { return __uint_as_float(u & 0xffff0000u); }

// K0: pack [W_src; W_skip] -> bf16 Wb[256][128]
__global__ __launch_bounds__(256) void k0_convert(
    const float* __restrict__ Wsrc, const float* __restrict__ Wskip,
    ushort* __restrict__ Wb)
{
    int i = blockIdx.x * 256 + threadIdx.x;   // 0..32767
    float v = (i < 16384) ? Wsrc[i] : Wskip[i - 16384];
    Wb[i] = f2bf(v);
}

// K1: bf16 MFMA projection GEMM. Block = 256 thr (4 waves), 64 rows of feat.
// Wave w computes rows[0:64) x cols [w*64, w*64+64) of the 256-wide output.
// cols 0..127 -> feat_src (bf16), cols 128..255 -> skip (fp32).
__global__ __launch_bounds__(256) void k1_mfma(
    const float* __restrict__ feat, const ushort* __restrict__ Wb,
    const float* __restrict__ bsrc, const float* __restrict__ bskip,
    ushort* __restrict__ feat_src, float* __restrict__ skip, int n)
{
    __shared__ ushort A_lds[64][136];          // pad +8 bf16 -> conflict-balanced b128
    const int tid = threadIdx.x;
    const int wave = tid >> 6, lane = tid & 63;
    const int quad = lane >> 4, l16 = lane & 15;
    const int row0 = blockIdx.x * 64;

    // stage 64x128 fp32 -> bf16 LDS; thread t: row t>>2, 32 cols at (t&3)*32
    {
        int r = tid >> 2;
        int c0 = (tid & 3) * 32;
        int grow = row0 + r;
        float4 f[8];
        if (grow < n) {
            const float4* p = (const float4*)(feat + (size_t)grow * 128 + c0);
            #pragma unroll
            for (int i = 0; i < 8; ++i) f[i] = p[i];
        } else {
            #pragma unroll
            for (int i = 0; i < 8; ++i) f[i] = make_float4(0.f, 0.f, 0.f, 0.f);
        }
        #pragma unroll
        for (int i = 0; i < 4; ++i) {
            short8 v;
            v[0] = (short)f2bf(f[2*i].x);   v[1] = (short)f2bf(f[2*i].y);
            v[2] = (short)f2bf(f[2*i].z);   v[3] = (short)f2bf(f[2*i].w);
            v[4] = (short)f2bf(f[2*i+1].x); v[5] = (short)f2bf(f[2*i+1].y);
            v[6] = (short)f2bf(f[2*i+1].z); v[7] = (short)f2bf(f[2*i+1].w);
            *(short8*)&A_lds[r][c0 + i * 8] = v;
        }
    }
    __syncthreads();

    v4f acc[4][4] = {};
    const int n0 = wave * 64;

    #pragma unroll
    for (int k0 = 0; k0 < 128; k0 += 32) {
        short8 a[4], b[4];
        #pragma unroll
        for (int mt = 0; mt < 4; ++mt)
            a[mt] = *(const short8*)&A_lds[mt * 16 + l16][k0 + quad * 8];
        #pragma unroll
        for (int nt = 0; nt < 4; ++nt) {
            int c = n0 + nt * 16 + l16;
            b[nt] = *(const short8*)(Wb + (size_t)c * 128 + k0 + quad * 8);
        }
        #pragma unroll
        for (int mt = 0; mt < 4; ++mt)
            #pragma unroll
            for (int nt = 0; nt < 4; ++nt)
                acc[mt][nt] = __builtin_amdgcn_mfma_f32_16x16x32_bf16(
                    a[mt], b[nt], acc[mt][nt], 0, 0, 0);
    }

    // epilogue: C[row=quad*4+i (+16mt), col=l16 (+16nt)] + bias
    #pragma unroll
    for (int nt = 0; nt < 4; ++nt) {
        int c = n0 + nt * 16 + l16;
        float bias = (c < 128) ? bsrc[c] : bskip[c - 128];
        #pragma unroll
        for (int mt = 0; mt < 4; ++mt) {
            #pragma unroll
            for (int i = 0; i < 4; ++i) {
                int row = row0 + mt * 16 + quad * 4 + i;
                if (row < n) {
                    float v = acc[mt][nt][i] + bias;
                    if (c < 128) feat_src[(size_t)row * 128 + c] = f2bf(v);
                    else         skip[(size_t)row * 128 + (c - 128)] = v;
                }
            }
        }
    }
}

// K1b: el/er attention dots from bf16 feat_src. One wave per node.
__global__ __launch_bounds__(256) void k1b_attn(
    const ushort* __restrict__ feat_src,
    const float* __restrict__ attn_l, const float* __restrict__ attn_r,
    float* __restrict__ el, float* __restrict__ er, int n)
{
    int node = blockIdx.x * 4 + (threadIdx.x >> 6);
    if (node >= n) return;
    int lane = threadIdx.x & 63;
    int j = lane * 2, h = lane >> 4;
    unsigned u = *(const unsigned*)(feat_src + (size_t)node * 128 + j);
    float f0 = bflo(u), f1 = bfhi(u);
    float pl = f0 * attn_l[j] + f1 * attn_l[j + 1];
    float pr = f0 * attn_r[j] + f1 * attn_r[j + 1];
    #pragma unroll
    for (int m = 1; m < 16; m <<= 1) {
        pl += __shfl_xor(pl, m);
        pr += __shfl_xor(pr, m);
    }
    if ((lane & 15) == 0) {
        el[(size_t)node * 4 + h] = pl;
        er[(size_t)node * 4 + h] = pr;
    }
}

// ---- CSR build: histogram -> 3-phase scan -> fill ----

__global__ __launch_bounds__(256) void k_hist(const int* __restrict__ dst,
                                              int* __restrict__ counts, int E_)
{
    int e = blockIdx.x * 256 + threadIdx.x;
    if (e < E_) atomicAdd(&counts[dst[e]], 1);
}

__global__ __launch_bounds__(256) void k_scanA(const int* __restrict__ counts,
                                               int* __restrict__ row_start,
                                               int* __restrict__ blocksum, int n)
{
    __shared__ int sdata[256];
    int tid = threadIdx.x;
    int base = blockIdx.x * 1024 + tid * 4;
    int v[4]; int s = 0;
    #pragma unroll
    for (int k = 0; k < 4; ++k) {
        int idx = base + k;
        v[k] = (idx < n) ? counts[idx] : 0;
        s += v[k];
    }
    sdata[tid] = s;
    __syncthreads();
    for (int off = 1; off < 256; off <<= 1) {
        int t = (tid >= off) ? sdata[tid - off] : 0;
        __syncthreads();
        sdata[tid] += t;
        __syncthreads();
    }
    if (tid == 255) blocksum[blockIdx.x] = sdata[255];
    int run = (tid > 0) ? sdata[tid - 1] : 0;
    #pragma unroll
    for (int k = 0; k < 4; ++k) {
        int idx = base + k;
        if (idx < n) row_start[idx] = run;
        run += v[k];
    }
}

__global__ __launch_bounds__(128) void k_scanB(int* __restrict__ blocksum, int nb)
{
    __shared__ int sdata[128];
    int tid = threadIdx.x;
    sdata[tid] = (tid < nb) ? blocksum[tid] : 0;
    __syncthreads();
    for (int off = 1; off < 128; off <<= 1) {
        int t = (tid >= off) ? sdata[tid - off] : 0;
        __syncthreads();
        sdata[tid] += t;
        __syncthreads();
    }
    if (tid < nb) blocksum[tid] = (tid > 0) ? sdata[tid - 1] : 0;
}

__global__ __launch_bounds__(256) void k_scanC(int* __restrict__ row_start,
                                               const int* __restrict__ blocksum,
                                               int* __restrict__ cursor, int n, int E_)
{
    int i = blockIdx.x * 256 + threadIdx.x;
    if (i < n) {
        int v = row_start[i] + blocksum[i >> 10];
        row_start[i] = v;
        cursor[i] = v;
    }
    if (i == n) row_start[n] = E_;
}

__global__ __launch_bounds__(256) void k_fill(const int* __restrict__ src,
                                              const int* __restrict__ dst,
                                              int* __restrict__ cursor,
                                              int* __restrict__ csr_src, int E_)
{
    int e = blockIdx.x * 256 + threadIdx.x;
    if (e >= E_) return;
    int pos = atomicAdd(&cursor[dst[e]], 1);
    csr_src[pos] = src[e];
}

// K3: fused softmax-aggregate + gate + LayerNorm + PReLU. One wave per dst node.
__global__ __launch_bounds__(256) void k3_fused(
    const int* __restrict__ row_start, const int* __restrict__ csr_src,
    const float* __restrict__ el, const float* __restrict__ er,
    const ushort* __restrict__ feat_src, const float* __restrict__ skip,
    const float* __restrict__ Wg, const float* __restrict__ bg,
    const float* __restrict__ lng, const float* __restrict__ lnb,
    const float* __restrict__ pa, float* __restrict__ out, int n)
{
    int node = blockIdx.x * 4 + (threadIdx.x >> 6);
    if (node >= n) return;
    int lane = threadIdx.x & 63;
    int j = lane * 2;
    int h = j >> 5;

    int beg = row_start[node], end = row_start[node + 1];
    float er_h = er[(size_t)node * 4 + h];

    float acc0 = 0.f, acc1 = 0.f, wsum = 0.f;
    for (int p = beg; p < end; ++p) {
        int s = csr_src[p];
        float t = el[(size_t)s * 4 + h] + er_h;
        float w = __expf(t >= 0.f ? t : 0.2f * t);
        wsum += w;
        unsigned u = *(const unsigned*)(feat_src + (size_t)s * 128 + j);
        acc0 = fmaf(w, bflo(u), acc0);
        acc1 = fmaf(w, bfhi(u), acc1);
    }
    float inv = (wsum > 0.f) ? 1.f / wsum : 0.f;
    float r0 = acc0 * inv, r1 = acc1 * inv;

    float2 s2 = *(const float2*)(skip + (size_t)node * 128 + j);

    float g = r0 * Wg[j]     + s2.x * Wg[128 + j]     + (r0 - s2.x) * Wg[256 + j]
            + r1 * Wg[j + 1] + s2.y * Wg[128 + j + 1] + (r1 - s2.y) * Wg[256 + j + 1];
    #pragma unroll
    for (int m = 1; m < 64; m <<= 1) g += __shfl_xor(g, m);
    float gate = 1.f / (1.f + __expf(-(g + bg[0])));

    float x0 = gate * r0 + (1.f - gate) * s2.x;
    float x1 = gate * r1 + (1.f - gate) * s2.y;

    float sm = x0 + x1, sq = x0 * x0 + x1 * x1;
    #pragma unroll
    for (int m = 1; m < 64; m <<= 1) {
        sm += __shfl_xor(sm, m);
        sq += __shfl_xor(sq, m);
    }
    float mu = sm * (1.f / 128.f);
    float var = sq * (1.f / 128.f) - mu * mu;
    float rs = rsqrtf(var + 1e-5f);
    float alpha = pa[0];
    float y0 = (x0 - mu) * rs * lng[j]     + lnb[j];
    float y1 = (x1 - mu) * rs * lng[j + 1] + lnb[j + 1];
    y0 = y0 >= 0.f ? y0 : alpha * y0;
    y1 = y1 >= 0.f ? y1 : alpha * y1;
    *(float2*)(out + (size_t)node * 128 + j) = make_float2(y0, y1);
}

extern "C" void kernel_launch(void* const* d_in, const int* in_sizes, int n_in,
                              void* d_out, int out_size, void* d_ws, size_t ws_size,
                              hipStream_t stream)
{
    const float* feat   = (const float*)d_in[0];
    const int*   src    = (const int*)d_in[1];
    const int*   dst    = (const int*)d_in[2];
    const float* Wsrc   = (const float*)d_in[3];
    const float* bsrc   = (const float*)d_in[4];
    const float* attn_l = (const float*)d_in[5];
    const float* attn_r = (const float*)d_in[6];
    const float* Wskip  = (const float*)d_in[7];
    const float* bskip  = (const float*)d_in[8];
    const float* Wg     = (const float*)d_in[9];
    const float* bg     = (const float*)d_in[10];
    const float* lng    = (const float*)d_in[11];
    const float* lnb    = (const float*)d_in[12];
    const float* pa     = (const float*)d_in[13];

    const int n = in_sizes[0] / 128;
    const int E = in_sizes[1];
    float* out = (float*)d_out;

    // workspace: skip f32[n*128] | el f32[n*4] | er f32[n*4] |
    //            feat_src bf16[n*128] | Wb bf16[32768] |
    //            counts[n] | row_start[n+1] | cursor[n] | blocksum[128] | csr_src[E]
    float*  skip     = (float*)d_ws;
    float*  el       = skip + (size_t)n * 128;
    float*  er       = el + (size_t)n * 4;
    ushort* feat_src = (ushort*)(er + (size_t)n * 4);
    ushort* Wb       = feat_src + (size_t)n * 128;
    int*    counts    = (int*)(Wb + 32768);
    int*    row_start = counts + n;
    int*    cursor    = row_start + (n + 1);
    int*    blocksum  = cursor + n;
    int*    csr_src   = blocksum + 128;

    hipMemsetAsync(counts, 0, (size_t)n * sizeof(int), stream);

    k0_convert<<<128, 256, 0, stream>>>(Wsrc, Wskip, Wb);
    k1_mfma<<<(n + 63) / 64, 256, 0, stream>>>(feat, Wb, bsrc, bskip, feat_src, skip, n);
    k1b_attn<<<(n + 3) / 4, 256, 0, stream>>>(feat_src, attn_l, attn_r, el, er, n);

    k_hist<<<(E + 255) / 256, 256, 0, stream>>>(dst, counts, E);
    int nb = (n + 1023) / 1024;
    k_scanA<<<nb, 256, 0, stream>>>(counts, row_start, blocksum, n);
    k_scanB<<<1, 128, 0, stream>>>(blocksum, nb);
    k_scanC<<<(n + 256) / 256, 256, 0, stream>>>(row_start, blocksum, cursor, n, E);
    k_fill<<<(E + 255) / 256, 256, 0, stream>>>(src, dst, cursor, csr_src, E);

    k3_fused<<<(n + 3) / 4, 256, 0, stream>>>(
        row_start, csr_src, el, er, feat_src, skip, Wg, bg, lng, lnb, pa, out, n);
}

// Round 4
// 304.653 us; speedup vs baseline: 2.6683x; 1.2202x over previous
//
#include <hip/hip_runtime.h>

typedef __attribute__((ext_vector_type(8))) short short8;
typedef __attribute__((ext_vector_type(4))) float v4f;

__device__ __forceinline__ ushort f2bf(float x) {
    unsigned u = __float_as_uint(x);
    u = u + 0x7fffu + ((u >> 16) & 1u);     // round-to-nearest-even
    return (ushort)(u >> 16);
}
__device__ __forceinline__ float bflo(unsigned u) { return __uint_as_float(u << 16); }
__device__ __forceinline__ float bfhi(unsigned u) { return __uint_as_float(u & 0xffff0000u); }

// K0: pack [W_src; W_skip] -> bf16 Wb[256][128], plus dst histogram (merged launch)
__global__ __launch_bounds__(256) void k0_misc(
    const float* __restrict__ Wsrc, const float* __restrict__ Wskip,
    ushort* __restrict__ Wb, const int* __restrict__ dst,
    int* __restrict__ counts, int E_)
{
    int b = blockIdx.x;
    if (b < 128) {
        int i = b * 256 + threadIdx.x;     // 0..32767
        float v = (i < 16384) ? Wsrc[i] : Wskip[i - 16384];
        Wb[i] = f2bf(v);
    } else {
        int e = (b - 128) * 256 + threadIdx.x;
        if (e < E_) atomicAdd(&counts[dst[e]], 1);
    }
}

// K1: bf16 MFMA projection GEMM + fused el/er attention dots.
// Block = 256 thr (4 waves), 64 rows. Wave w: cols [w*64, w*64+64).
// cols 0..127 -> feat_src (bf16) + el/er; cols 128..255 -> skip (bf16).
__global__ __launch_bounds__(256) void k1_mfma(
    const float* __restrict__ feat, const ushort* __restrict__ Wb,
    const float* __restrict__ bsrc, const float* __restrict__ bskip,
    const float* __restrict__ attn_l, const float* __restrict__ attn_r,
    ushort* __restrict__ feat_src, ushort* __restrict__ skip_bf,
    float* __restrict__ el, float* __restrict__ er, int n)
{
    __shared__ ushort A_lds[64][136];          // pad +8 -> conflict-balanced b128
    const int tid = threadIdx.x;
    const int wave = tid >> 6, lane = tid & 63;
    const int quad = lane >> 4, l16 = lane & 15;
    const int row0 = blockIdx.x * 64;

    // stage 64x128 fp32 -> bf16 LDS
    {
        int r = tid >> 2;
        int c0 = (tid & 3) * 32;
        int grow = row0 + r;
        float4 f[8];
        if (grow < n) {
            const float4* p = (const float4*)(feat + (size_t)grow * 128 + c0);
            #pragma unroll
            for (int i = 0; i < 8; ++i) f[i] = p[i];
        } else {
            #pragma unroll
            for (int i = 0; i < 8; ++i) f[i] = make_float4(0.f, 0.f, 0.f, 0.f);
        }
        #pragma unroll
        for (int i = 0; i < 4; ++i) {
            short8 v;
            v[0] = (short)f2bf(f[2*i].x);   v[1] = (short)f2bf(f[2*i].y);
            v[2] = (short)f2bf(f[2*i].z);   v[3] = (short)f2bf(f[2*i].w);
            v[4] = (short)f2bf(f[2*i+1].x); v[5] = (short)f2bf(f[2*i+1].y);
            v[6] = (short)f2bf(f[2*i+1].z); v[7] = (short)f2bf(f[2*i+1].w);
            *(short8*)&A_lds[r][c0 + i * 8] = v;
        }
    }
    __syncthreads();

    v4f acc[4][4] = {};
    const int n0 = wave * 64;

    #pragma unroll
    for (int k0 = 0; k0 < 128; k0 += 32) {
        short8 a[4], b[4];
        #pragma unroll
        for (int mt = 0; mt < 4; ++mt)
            a[mt] = *(const short8*)&A_lds[mt * 16 + l16][k0 + quad * 8];
        #pragma unroll
        for (int nt = 0; nt < 4; ++nt) {
            int c = n0 + nt * 16 + l16;
            b[nt] = *(const short8*)(Wb + (size_t)c * 128 + k0 + quad * 8);
        }
        #pragma unroll
        for (int mt = 0; mt < 4; ++mt)
            #pragma unroll
            for (int nt = 0; nt < 4; ++nt)
                acc[mt][nt] = __builtin_amdgcn_mfma_f32_16x16x32_bf16(
                    a[mt], b[nt], acc[mt][nt], 0, 0, 0);
    }

    // add bias in place
    #pragma unroll
    for (int nt = 0; nt < 4; ++nt) {
        int c = n0 + nt * 16 + l16;
        float bias = (c < 128) ? bsrc[c] : bskip[c - 128];
        #pragma unroll
        for (int mt = 0; mt < 4; ++mt)
            #pragma unroll
            for (int i = 0; i < 4; ++i)
                acc[mt][nt][i] += bias;
    }

    // store: C[row = mt*16 + quad*4 + i][col = n0 + nt*16 + l16], bf16
    #pragma unroll
    for (int nt = 0; nt < 4; ++nt) {
        int c = n0 + nt * 16 + l16;
        #pragma unroll
        for (int mt = 0; mt < 4; ++mt) {
            #pragma unroll
            for (int i = 0; i < 4; ++i) {
                int row = row0 + mt * 16 + quad * 4 + i;
                if (row < n) {
                    ushort v = f2bf(acc[mt][nt][i]);
                    if (c < 128) feat_src[(size_t)row * 128 + c] = v;
                    else         skip_bf[(size_t)row * 128 + (c - 128)] = v;
                }
            }
        }
    }

    // fused el/er: waves 0,1 cover feat_src cols; head h cols [h*32,h*32+32)
    // lie entirely in one wave's slab (nt 0,1 -> head hb, nt 2,3 -> head hb+1).
    if (wave < 2) {
        const int hb = n0 >> 5;
        float al0 = attn_l[n0 + l16],      al1 = attn_l[n0 + 16 + l16];
        float al2 = attn_l[n0 + 32 + l16], al3 = attn_l[n0 + 48 + l16];
        float ar0 = attn_r[n0 + l16],      ar1 = attn_r[n0 + 16 + l16];
        float ar2 = attn_r[n0 + 32 + l16], ar3 = attn_r[n0 + 48 + l16];
        #pragma unroll
        for (int mt = 0; mt < 4; ++mt) {
            #pragma unroll
            for (int i = 0; i < 4; ++i) {
                float pl0 = acc[mt][0][i] * al0 + acc[mt][1][i] * al1;
                float pl1 = acc[mt][2][i] * al2 + acc[mt][3][i] * al3;
                float pr0 = acc[mt][0][i] * ar0 + acc[mt][1][i] * ar1;
                float pr1 = acc[mt][2][i] * ar2 + acc[mt][3][i] * ar3;
                #pragma unroll
                for (int m = 1; m < 16; m <<= 1) {
                    pl0 += __shfl_xor(pl0, m); pl1 += __shfl_xor(pl1, m);
                    pr0 += __shfl_xor(pr0, m); pr1 += __shfl_xor(pr1, m);
                }
                int row = row0 + mt * 16 + quad * 4 + i;
                if (l16 == 0 && row < n) {
                    *(float2*)(el + (size_t)row * 4 + hb) = make_float2(pl0, pl1);
                    *(float2*)(er + (size_t)row * 4 + hb) = make_float2(pr0, pr1);
                }
            }
        }
    }
}

// ---- CSR build: scan + fill ----

__global__ __launch_bounds__(256) void k_scanA(const int* __restrict__ counts,
                                               int* __restrict__ row_start,
                                               int* __restrict__ blocksum, int n)
{
    __shared__ int sdata[256];
    int tid = threadIdx.x;
    int base = blockIdx.x * 1024 + tid * 4;
    int v[4]; int s = 0;
    #pragma unroll
    for (int k = 0; k < 4; ++k) {
        int idx = base + k;
        v[k] = (idx < n) ? counts[idx] : 0;
        s += v[k];
    }
    sdata[tid] = s;
    __syncthreads();
    for (int off = 1; off < 256; off <<= 1) {
        int t = (tid >= off) ? sdata[tid - off] : 0;
        __syncthreads();
        sdata[tid] += t;
        __syncthreads();
    }
    if (tid == 255) blocksum[blockIdx.x] = sdata[255];
    int run = (tid > 0) ? sdata[tid - 1] : 0;
    #pragma unroll
    for (int k = 0; k < 4; ++k) {
        int idx = base + k;
        if (idx < n) row_start[idx] = run;
        run += v[k];
    }
}

__global__ __launch_bounds__(128) void k_scanB(int* __restrict__ blocksum, int nb)
{
    __shared__ int sdata[128];
    int tid = threadIdx.x;
    sdata[tid] = (tid < nb) ? blocksum[tid] : 0;
    __syncthreads();
    for (int off = 1; off < 128; off <<= 1) {
        int t = (tid >= off) ? sdata[tid - off] : 0;
        __syncthreads();
        sdata[tid] += t;
        __syncthreads();
    }
    if (tid < nb) blocksum[tid] = (tid > 0) ? sdata[tid - 1] : 0;
}

__global__ __launch_bounds__(256) void k_scanC(int* __restrict__ row_start,
                                               const int* __restrict__ blocksum,
                                               int* __restrict__ cursor, int n, int E_)
{
    int i = blockIdx.x * 256 + threadIdx.x;
    if (i < n) {
        int v = row_start[i] + blocksum[i >> 10];
        row_start[i] = v;
        cursor[i] = v;
    }
    if (i == n) row_start[n] = E_;
}

__global__ __launch_bounds__(256) void k_fill(const int* __restrict__ src,
                                              const int* __restrict__ dst,
                                              int* __restrict__ cursor,
                                              int* __restrict__ csr_src, int E_)
{
    int e = blockIdx.x * 256 + threadIdx.x;
    if (e >= E_) return;
    int pos = atomicAdd(&cursor[dst[e]], 1);
    csr_src[pos] = src[e];
}

// K3: fused softmax-aggregate + gate + LayerNorm + PReLU. One wave per dst node.
// Edge indices batch-loaded (one coalesced read per 64 edges) and broadcast via
// shfl; 4-wide unrolled gather loop with independent accumulators for MLP.
__global__ __launch_bounds__(256) void k3_fused(
    const int* __restrict__ row_start, const int* __restrict__ csr_src,
    const float* __restrict__ el, const float* __restrict__ er,
    const ushort* __restrict__ feat_src, const ushort* __restrict__ skip_bf,
    const float* __restrict__ Wg, const float* __restrict__ bg,
    const float* __restrict__ lng, const float* __restrict__ lnb,
    const float* __restrict__ pa, float* __restrict__ out, int n)
{
    int node = blockIdx.x * 4 + (threadIdx.x >> 6);
    if (node >= n) return;
    int lane = threadIdx.x & 63;
    int j = lane * 2;
    int h = j >> 5;

    int beg = row_start[node], end = row_start[node + 1];
    float er_h = er[(size_t)node * 4 + h];
    const ushort* fbase = feat_src + j;

    float a0 = 0.f, a1 = 0.f, b0 = 0.f, b1 = 0.f;
    float c0 = 0.f, c1 = 0.f, d0 = 0.f, d1 = 0.f;
    float ws0 = 0.f, ws1 = 0.f, ws2 = 0.f, ws3 = 0.f;

    for (int p0 = beg; p0 < end; p0 += 64) {
        int pv = p0 + lane;
        int sv = csr_src[pv < end ? pv : end - 1];   // one coalesced load / 64 edges
        int cnt = end - p0; if (cnt > 64) cnt = 64;
        int i = 0;
        for (; i + 3 < cnt; i += 4) {
            int s0 = __shfl(sv, i),     s1 = __shfl(sv, i + 1);
            int s2 = __shfl(sv, i + 2), s3 = __shfl(sv, i + 3);
            float e0 = el[(size_t)s0 * 4 + h];
            float e1 = el[(size_t)s1 * 4 + h];
            float e2 = el[(size_t)s2 * 4 + h];
            float e3 = el[(size_t)s3 * 4 + h];
            unsigned u0 = *(const unsigned*)(fbase + (size_t)s0 * 128);
            unsigned u1 = *(const unsigned*)(fbase + (size_t)s1 * 128);
            unsigned u2 = *(const unsigned*)(fbase + (size_t)s2 * 128);
            unsigned u3 = *(const unsigned*)(fbase + (size_t)s3 * 128);
            float t0 = e0 + er_h, t1 = e1 + er_h, t2 = e2 + er_h, t3 = e3 + er_h;
            float w0 = __expf(t0 >= 0.f ? t0 : 0.2f * t0);
            float w1 = __expf(t1 >= 0.f ? t1 : 0.2f * t1);
            float w2 = __expf(t2 >= 0.f ? t2 : 0.2f * t2);
            float w3 = __expf(t3 >= 0.f ? t3 : 0.2f * t3);
            ws0 += w0; ws1 += w1; ws2 += w2; ws3 += w3;
            a0 = fmaf(w0, bflo(u0), a0); a1 = fmaf(w0, bfhi(u0), a1);
            b0 = fmaf(w1, bflo(u1), b0); b1 = fmaf(w1, bfhi(u1), b1);
            c0 = fmaf(w2, bflo(u2), c0); c1 = fmaf(w2, bfhi(u2), c1);
            d0 = fmaf(w3, bflo(u3), d0); d1 = fmaf(w3, bfhi(u3), d1);
        }
        for (; i < cnt; ++i) {
            int s = __shfl(sv, i);
            float t = el[(size_t)s * 4 + h] + er_h;
            float w = __expf(t >= 0.f ? t : 0.2f * t);
            unsigned u = *(const unsigned*)(fbase + (size_t)s * 128);
            ws0 += w;
            a0 = fmaf(w, bflo(u), a0); a1 = fmaf(w, bfhi(u), a1);
        }
    }
    float wsum = (ws0 + ws1) + (ws2 + ws3);
    float acc0 = (a0 + b0) + (c0 + d0);
    float acc1 = (a1 + b1) + (c1 + d1);
    float inv = (wsum > 0.f) ? 1.f / wsum : 0.f;   // deg-0 node -> rst = 0
    float r0 = acc0 * inv, r1 = acc1 * inv;

    unsigned su = *(const unsigned*)(skip_bf + (size_t)node * 128 + j);
    float sx = bflo(su), sy = bfhi(su);

    float g = r0 * Wg[j]     + sx * Wg[128 + j]     + (r0 - sx) * Wg[256 + j]
            + r1 * Wg[j + 1] + sy * Wg[128 + j + 1] + (r1 - sy) * Wg[256 + j + 1];
    #pragma unroll
    for (int m = 1; m < 64; m <<= 1) g += __shfl_xor(g, m);
    float gate = 1.f / (1.f + __expf(-(g + bg[0])));

    float x0 = gate * r0 + (1.f - gate) * sx;
    float x1 = gate * r1 + (1.f - gate) * sy;

    float sm = x0 + x1, sq = x0 * x0 + x1 * x1;
    #pragma unroll
    for (int m = 1; m < 64; m <<= 1) {
        sm += __shfl_xor(sm, m);
        sq += __shfl_xor(sq, m);
    }
    float mu = sm * (1.f / 128.f);
    float var = sq * (1.f / 128.f) - mu * mu;
    float rs = rsqrtf(var + 1e-5f);
    float alpha = pa[0];
    float y0 = (x0 - mu) * rs * lng[j]     + lnb[j];
    float y1 = (x1 - mu) * rs * lng[j + 1] + lnb[j + 1];
    y0 = y0 >= 0.f ? y0 : alpha * y0;
    y1 = y1 >= 0.f ? y1 : alpha * y1;
    *(float2*)(out + (size_t)node * 128 + j) = make_float2(y0, y1);
}

extern "C" void kernel_launch(void* const* d_in, const int* in_sizes, int n_in,
                              void* d_out, int out_size, void* d_ws, size_t ws_size,
                              hipStream_t stream)
{
    const float* feat   = (const float*)d_in[0];
    const int*   src    = (const int*)d_in[1];
    const int*   dst    = (const int*)d_in[2];
    const float* Wsrc   = (const float*)d_in[3];
    const float* bsrc   = (const float*)d_in[4];
    const float* attn_l = (const float*)d_in[5];
    const float* attn_r = (const float*)d_in[6];
    const float* Wskip  = (const float*)d_in[7];
    const float* bskip  = (const float*)d_in[8];
    const float* Wg     = (const float*)d_in[9];
    const float* bg     = (const float*)d_in[10];
    const float* lng    = (const float*)d_in[11];
    const float* lnb    = (const float*)d_in[12];
    const float* pa     = (const float*)d_in[13];

    const int n = in_sizes[0] / 128;
    const int E = in_sizes[1];
    float* out = (float*)d_out;

    // workspace: el f32[n*4] | er f32[n*4] | feat_src bf16[n*128] |
    //            skip bf16[n*128] | Wb bf16[32768] |
    //            counts[n] | row_start[n+1] | cursor[n] | blocksum[128] | csr_src[E]
    float*  el       = (float*)d_ws;
    float*  er       = el + (size_t)n * 4;
    ushort* feat_src = (ushort*)(er + (size_t)n * 4);
    ushort* skip_bf  = feat_src + (size_t)n * 128;
    ushort* Wb       = skip_bf + (size_t)n * 128;
    int*    counts    = (int*)(Wb + 32768);
    int*    row_start = counts + n;
    int*    cursor    = row_start + (n + 1);
    int*    blocksum  = cursor + n;
    int*    csr_src   = blocksum + 128;

    hipMemsetAsync(counts, 0, (size_t)n * sizeof(int), stream);

    k0_misc<<<128 + (E + 255) / 256, 256, 0, stream>>>(Wsrc, Wskip, Wb, dst, counts, E);
    k1_mfma<<<(n + 63) / 64, 256, 0, stream>>>(
        feat, Wb, bsrc, bskip, attn_l, attn_r, feat_src, skip_bf, el, er, n);

    int nb = (n + 1023) / 1024;
    k_scanA<<<nb, 256, 0, stream>>>(counts, row_start, blocksum, n);
    k_scanB<<<1, 128, 0, stream>>>(blocksum, nb);
    k_scanC<<<(n + 256) / 256, 256, 0, stream>>>(row_start, blocksum, cursor, n, E);
    k_fill<<<(E + 255) / 256, 256, 0, stream>>>(src, dst, cursor, csr_src, E);

    k3_fused<<<(n + 3) / 4, 256, 0, stream>>>(
        row_start, csr_src, el, er, feat_src, skip_bf, Wg, bg, lng, lnb, pa, out, n);
}